// Round 1
// 271.512 us; speedup vs baseline: 1.0064x; 1.0064x over previous
//
#include <hip/hip_runtime.h>
#include <math.h>

#define EPSQ 1e-7f
#define TDIM 2000
#define CDIM 128
#define LDIM 200
#define SPL  7
#define SENTE (-(1 << 30))

// LDS int-index map (per block: ONE stream - alpha or beta)
#define RING  0        // 16384 floats (64KB): ring of 128 rows x 128 floats, row r -> (r & 127)
#define LABSI 16384    // 200 ints
#define PRODF 16584    // pairs (alpha) / k-items (beta) produced
#define CONSF 16585    // pairs / k-items fully consumed
#define SMEMN 16592

// workspace layout per batch: 1024 floats.
// [0..447] alpha vals (lane*7+j), int[448..511] alpha exps,
// [512..959] beta vals,           int[960..1023] beta exps.

__device__ __forceinline__ float dpp_shr_f(float x) { // lane i <- lane i-1, lane0 <- 0
    return __int_as_float(__builtin_amdgcn_update_dpp(0, __float_as_int(x), 0x138, 0xf, 0xf, true));
}
__device__ __forceinline__ int dpp_shr_i(int x) {
    return __builtin_amdgcn_update_dpp(0, x, 0x138, 0xf, 0xf, true);
}
__device__ __forceinline__ float dpp_shl_f(float x) { // lane i <- lane i+1, lane63 <- 0
    return __int_as_float(__builtin_amdgcn_update_dpp(0, __float_as_int(x), 0x130, 0xf, 0xf, true));
}
__device__ __forceinline__ int dpp_shl_i(int x) {
    return __builtin_amdgcn_update_dpp(0, x, 0x130, 0xf, 0xf, true);
}

// ---- alpha renorm (verified): per-lane BFP, neighbor = lane-1
__device__ __forceinline__ void renorm_alpha(float a[SPL], int& E, float& fprev, int lane) {
    float mx = fmaxf(fmaxf(fmaxf(a[0], a[1]), fmaxf(a[2], a[3])),
                     fmaxf(fmaxf(a[4], a[5]), a[6]));
    bool zero = (mx == 0.f);
    int e = ((__float_as_int(mx) >> 23) & 0xff) - 127;
    int S_self = zero ? SENTE : (E + e);
    int S1 = dpp_shr_i(S_self);
    if (lane == 0) S1 = SENTE;
    int S2 = dpp_shr_i(S1);
    if (lane == 0) S2 = SENTE;
    int E_new = max(S_self, S1);
    int E_prevnew = max(S1, S2);
    int dg = E - E_new;
    float g = (zero || dg < -126) ? 0.f : __int_as_float((dg + 127) << 23);
#pragma unroll
    for (int j = 0; j < SPL; ++j) a[j] *= g;
    E = E_new;
    int df = E_prevnew - E_new;
    bool fz = (E_prevnew <= SENTE / 2) || (df < -126);
    if (df > 126) df = 126;
    fprev = fz ? 0.f : __int_as_float((df + 127) << 23);
}

// ---- beta renorm: mirror, neighbor = lane+1
__device__ __forceinline__ void renorm_beta(float b[SPL], int& E, float& fnext, int lane) {
    float mx = fmaxf(fmaxf(fmaxf(b[0], b[1]), fmaxf(b[2], b[3])),
                     fmaxf(fmaxf(b[4], b[5]), b[6]));
    bool zero = (mx == 0.f);
    int e = ((__float_as_int(mx) >> 23) & 0xff) - 127;
    int S_self = zero ? SENTE : (E + e);
    int S1 = dpp_shl_i(S_self);
    if (lane == 63) S1 = SENTE;
    int S2 = dpp_shl_i(S1);
    if (lane == 63) S2 = SENTE;
    int E_new = max(S_self, S1);
    int E_nextnew = max(S1, S2);
    int dg = E - E_new;
    float g = (zero || dg < -126) ? 0.f : __int_as_float((dg + 127) << 23);
#pragma unroll
    for (int j = 0; j < SPL; ++j) b[j] *= g;
    E = E_new;
    int df = E_nextnew - E_new;
    bool fz = (E_nextnew <= SENTE / 2) || (df < -126);
    if (df > 126) df = 126;
    fnext = fz ? 0.f : __int_as_float((df + 127) << 23);
}

// alpha step: consumes row t+TOFF (slot (t+TOFF)&3 = (1+TOFF)&3 since t%16==1),
// issues 3-ahead gathers for row t+TOFF+3 into slot (TOFF)&3 (freed last step).
#define A_STEP(TOFF) do {                                                     \
    float p6 = dpp_shr_f(a[6]) * fprev;                                       \
    float p5 = dpp_shr_f(a[5]) * fprev;                                       \
    float n0 = fmaf(skipf[0], p5,   a[0] + p6)   * q[(1+(TOFF))&3][0];        \
    float n1 = fmaf(skipf[1], p6,   a[1] + a[0]) * q[(1+(TOFF))&3][1];        \
    float n2 = fmaf(skipf[2], a[0], a[2] + a[1]) * q[(1+(TOFF))&3][2];        \
    float n3 = fmaf(skipf[3], a[1], a[3] + a[2]) * q[(1+(TOFF))&3][3];        \
    float n4 = fmaf(skipf[4], a[2], a[4] + a[3]) * q[(1+(TOFF))&3][4];        \
    float n5 = fmaf(skipf[5], a[3], a[5] + a[4]) * q[(1+(TOFF))&3][5];        \
    float n6 = fmaf(skipf[6], a[4], a[6] + a[5]) * q[(1+(TOFF))&3][6];        \
    a[0]=n0; a[1]=n1; a[2]=n2; a[3]=n3; a[4]=n4; a[5]=n5; a[6]=n6;            \
    if (t + (TOFF) == m) {                                                    \
        _Pragma("unroll")                                                     \
        for (int j = 0; j < SPL; ++j) ac[j] = a[j];                           \
        Eac = E;                                                              \
    }                                                                         \
    {   const int rr = ((t + (TOFF) + 3) & 127) << 7;                         \
        _Pragma("unroll")                                                     \
        for (int j = 0; j < SPL; ++j)                                         \
            q[(TOFF)&3][j] = ring[rr + cls[j]];                               \
    }                                                                         \
} while (0);

// beta step: consumes row t0-(s+SOFF), slot (SOFF)&3 (s%16==0);
// issues 3-ahead gathers for row t0-(s+SOFF)-3 into slot (3+SOFF)&3.
#define B_STEP(SOFF) do {                                                     \
    float c0 = bb[0]*q[(SOFF)&3][0], c1 = bb[1]*q[(SOFF)&3][1];               \
    float c2 = bb[2]*q[(SOFF)&3][2], c3 = bb[3]*q[(SOFF)&3][3];               \
    float c4 = bb[4]*q[(SOFF)&3][4], c5 = bb[5]*q[(SOFF)&3][5];               \
    float c6 = bb[6]*q[(SOFF)&3][6];                                          \
    float cn0 = dpp_shl_f(c0) * fnext;                                        \
    float cn1 = dpp_shl_f(c1) * fnext;                                        \
    bb[0] = fmaf(skb[0], c2, c0 + c1);                                        \
    bb[1] = fmaf(skb[1], c3, c1 + c2);                                        \
    bb[2] = fmaf(skb[2], c4, c2 + c3);                                        \
    bb[3] = fmaf(skb[3], c5, c3 + c4);                                        \
    bb[4] = fmaf(skb[4], c6, c4 + c5);                                        \
    bb[5] = fmaf(skb[5], cn0, c5 + c6);                                       \
    bb[6] = fmaf(skb[6], cn1, c6 + cn0);                                      \
    if (s + (SOFF) == scap) {                                                 \
        _Pragma("unroll")                                                     \
        for (int j = 0; j < SPL; ++j) bc[j] = bb[j];                          \
        Ebc = E;                                                              \
    }                                                                         \
    {   const int rr = ((t0 - s - (SOFF) - 3) & 127) << 7;                    \
        _Pragma("unroll")                                                     \
        for (int j = 0; j < SPL; ++j)                                         \
            q[(3+(SOFF))&3][j] = ring[rr + cls[j]];                           \
    }                                                                         \
} while (0);

// producer load/store of a group of 8 pairs (pair = 2 rows = 1KB).
// pair index: role 0 -> ii ascending; role 1 -> pbase - ii descending.
#define LOADG(W, G) do {                                                      \
    _Pragma("unroll")                                                         \
    for (int i_ = 0; i_ < 8; ++i_) {                                          \
        int ii_ = (G) * 8 + i_; if (ii_ > iend) ii_ = iend;                   \
        int pr_ = role ? (pbase - ii_) : ii_;                                 \
        W[i_] = rp4[pr_ * 64 + lane];                                         \
    }                                                                         \
} while (0)

#define STOREG(W, G) do {                                                     \
    _Pragma("unroll")                                                         \
    for (int i_ = 0; i_ < 8; ++i_) {                                          \
        int ii_ = (G) * 8 + i_; if (ii_ > iend) ii_ = iend;                   \
        int pr_ = role ? (pbase - ii_) : ii_;                                 \
        float4 x_ = W[i_];                                                    \
        x_.x += EPSQ; x_.y += EPSQ; x_.z += EPSQ; x_.w += EPSQ;               \
        *(float4*)&smf[RING + (pr_ & 63) * 256 + lane * 4] = x_;              \
    }                                                                         \
} while (0)

__global__ void __launch_bounds__(128, 1)
__attribute__((amdgpu_waves_per_eu(1, 1)))
ctc_kernel(const float* __restrict__ y_pred,
           const int* __restrict__ labels,
           const int* __restrict__ feat_lens,
           const int* __restrict__ label_lens,
           float* __restrict__ ws)
{
    __shared__ int smem[SMEMN];
    float* smf = (float*)smem;
    volatile int* vsm = (volatile int*)smem;

    const int bid = blockIdx.x;
    const int b = bid >> 1;
    const int role = bid & 1;          // 0 = alpha block, 1 = beta block
    const int tid = threadIdx.x;
    const int lane = tid & 63;
    const int wv = tid >> 6;

    int f = feat_lens[b];
    f = (f + 1) >> 1; f = (f + 1) >> 1;
    const int Tbm1 = f - 1;
    const int m = f >> 1;             // alpha: steps 1..m; beta: rows Tbm1..m+1

    if (tid < 2) smem[PRODF + tid] = 0;
    const int* labrow = labels + b * LDIM;
    for (int i = tid; i < LDIM; i += 128) smem[LABSI + i] = labrow[i];
    __syncthreads();

    const float4* rp4 = (const float4*)(y_pred + (size_t)b * TDIM * CDIM);

    if (wv == 1) {
        // ---------------- producer: 2-deep software pipeline ----------------
        int iend, pbase;
        if (role == 0) { iend = (m + 18) >> 1; pbase = 0; }
        else {
            const int pstart = Tbm1 >> 1;
            int pl = (m - 18) >> 1; if (pl < 0) pl = 0;
            iend = pstart - pl; pbase = pstart;
        }
        const int ng = (iend >> 3) + 1;
        float4 w0[8], w1[8];
        LOADG(w0, 0);
        if (ng > 1) LOADG(w1, 1);
        int g = 0;
        while (true) {
            while (vsm[CONSF] + 64 < 8 * (g + 1)) __builtin_amdgcn_s_sleep(2);
            asm volatile("" ::: "memory");
            STOREG(w0, g);
            asm volatile("s_waitcnt lgkmcnt(0)" ::: "memory");
            vsm[PRODF] = 8 * (g + 1);
            if (g + 2 < ng) LOADG(w0, g + 2);
            ++g; if (g >= ng) break;
            while (vsm[CONSF] + 64 < 8 * (g + 1)) __builtin_amdgcn_s_sleep(2);
            asm volatile("" ::: "memory");
            STOREG(w1, g);
            asm volatile("s_waitcnt lgkmcnt(0)" ::: "memory");
            vsm[PRODF] = 8 * (g + 1);
            if (g + 2 < ng) LOADG(w1, g + 2);
            ++g; if (g >= ng) break;
        }
        return;
    }

    // ---------------- consumer: per-lane state tables ----------------
    const int llen = label_lens[b];
    const int i1 = 2 * llen - 1, i2 = 2 * llen;
    int cls[SPL]; float skipf[SPL];
    const int s0 = lane * SPL;
#pragma unroll
    for (int j = 0; j < SPL; ++j) {
        int s = s0 + j;
        int c = CDIM - 1; float sk = 0.f;
        if (s < (2 * LDIM + 1) && (s & 1)) {
            int kk = s >> 1;
            c = smem[LABSI + kk];
            if (kk >= 1 && smem[LABSI + kk] != smem[LABSI + kk - 1]) sk = 1.f;
        }
        cls[j] = c; skipf[j] = sk;
    }
    const float* ring = &smf[RING];

    if (role == 0) {
        // ================= alpha (t = 0..m) =================
        float a[SPL], q[4][SPL], ac[SPL];
        int E = 0, Eac = 0;
        float fprev = 0.f;
#pragma unroll
        for (int j = 0; j < SPL; ++j) { a[j] = 0.f; ac[j] = 0.f; }

        while (vsm[PRODF] < 2) __builtin_amdgcn_s_sleep(1);
        asm volatile("" ::: "memory");
#pragma unroll
        for (int j = 0; j < SPL; ++j) {
            q[0][j] = ring[(0 << 7) + cls[j]];
            q[1][j] = ring[(1 << 7) + cls[j]];
            q[2][j] = ring[(2 << 7) + cls[j]];
            q[3][j] = ring[(3 << 7) + cls[j]];
        }
        if (lane == 0) { a[0] = q[0][0]; a[1] = q[0][1]; }

        int t = 1;
        while (t <= m) {
            vsm[CONSF] = (t >= 2) ? (((t - 2) >> 1) + 1) : 0;
            int need = ((t + 18) >> 1) + 1;
            while (vsm[PRODF] < need) __builtin_amdgcn_s_sleep(1);
            asm volatile("" ::: "memory");
            renorm_alpha(a, E, fprev, lane);
            A_STEP(0) A_STEP(1) A_STEP(2) A_STEP(3)
            renorm_alpha(a, E, fprev, lane);
            A_STEP(4) A_STEP(5) A_STEP(6) A_STEP(7)
            renorm_alpha(a, E, fprev, lane);
            A_STEP(8) A_STEP(9) A_STEP(10) A_STEP(11)
            renorm_alpha(a, E, fprev, lane);
            A_STEP(12) A_STEP(13) A_STEP(14) A_STEP(15)
            t += 16;
        }
        vsm[CONSF] = 1 << 28;
        asm volatile("" ::: "memory");
        float* wsb = ws + (size_t)b * 1024;
#pragma unroll
        for (int j = 0; j < SPL; ++j) wsb[lane * SPL + j] = ac[j];
        ((int*)wsb)[448 + lane] = Eac;
    } else {
        // ================= beta (rows Tbm1 down to m+1) =================
        float bb[SPL], q[4][SPL], bc[SPL];
        int E = 0, Ebc = 0;
        float fnext = 0.f;
#pragma unroll
        for (int j = 0; j < SPL; ++j) {
            int s = s0 + j;
            bb[j] = (s == i1 || s == i2) ? 1.f : 0.f;
            bc[j] = 0.f;
        }
        float skb[SPL];
#pragma unroll
        for (int j = 0; j < 5; ++j) skb[j] = skipf[j + 2];
        skb[5] = (lane == 63) ? 0.f : __shfl_down(skipf[0], 1, 64);
        skb[6] = (lane == 63) ? 0.f : __shfl_down(skipf[1], 1, 64);

        const int t0 = Tbm1;
        const int nb = t0 - m;       // number of steps (>= 1)
        const int scap = nb - 1;
        const int pstart = t0 >> 1;

        while (vsm[PRODF] < 2) __builtin_amdgcn_s_sleep(1);
        asm volatile("" ::: "memory");
#pragma unroll
        for (int j = 0; j < SPL; ++j) {
            q[0][j] = ring[((t0 & 127) << 7) + cls[j]];
            q[1][j] = ring[(((t0 - 1) & 127) << 7) + cls[j]];
            q[2][j] = ring[(((t0 - 2) & 127) << 7) + cls[j]];
            // q[3] (row t0-3) filled by B_STEP(0)'s prefetch before first read
            q[3][j] = 0.f;
        }

        int s = 0;
        while (s < nb) {
            int tcur = t0 - s;
            vsm[CONSF] = pstart - ((tcur + 2) >> 1) + 1;
            int need = pstart - ((tcur - 18) >> 1) + 1;
            while (vsm[PRODF] < need) __builtin_amdgcn_s_sleep(1);
            asm volatile("" ::: "memory");
            renorm_beta(bb, E, fnext, lane);
            B_STEP(0) B_STEP(1) B_STEP(2) B_STEP(3)
            renorm_beta(bb, E, fnext, lane);
            B_STEP(4) B_STEP(5) B_STEP(6) B_STEP(7)
            renorm_beta(bb, E, fnext, lane);
            B_STEP(8) B_STEP(9) B_STEP(10) B_STEP(11)
            renorm_beta(bb, E, fnext, lane);
            B_STEP(12) B_STEP(13) B_STEP(14) B_STEP(15)
            s += 16;
        }
        vsm[CONSF] = 1 << 28;
        asm volatile("" ::: "memory");
        float* wsb = ws + (size_t)b * 1024 + 512;
#pragma unroll
        for (int j = 0; j < SPL; ++j) wsb[lane * SPL + j] = bc[j];
        ((int*)wsb)[448 + lane] = Ebc;
    }
}

__global__ void __launch_bounds__(64, 1)
ctc_combine(const float* __restrict__ ws, float* __restrict__ out)
{
    const int b = blockIdx.x;
    const int lane = threadIdx.x & 63;
    const float* wa = ws + (size_t)b * 1024;
    const float* wb = wa + 512;
    const int Ea = ((const int*)wa)[448 + lane];
    const int Eb = ((const int*)wb)[448 + lane];
    float dot = 0.f;
#pragma unroll
    for (int j = 0; j < SPL; ++j)
        dot = fmaf(wa[lane * SPL + j], wb[lane * SPL + j], dot);
    float l2 = (dot > 0.f) ? (log2f(dot) + (float)(Ea + Eb)) : -1e30f;
    float M = l2;
#pragma unroll
    for (int d = 1; d < 64; d <<= 1) M = fmaxf(M, __shfl_xor(M, d, 64));
    float S = exp2f(l2 - M);
#pragma unroll
    for (int d = 1; d < 64; d <<= 1) S += __shfl_xor(S, d, 64);
    if (lane == 0) out[b] = -(M + log2f(S)) * 0.69314718055994530942f;
}

extern "C" void kernel_launch(void* const* d_in, const int* in_sizes, int n_in,
                              void* d_out, int out_size, void* d_ws, size_t ws_size,
                              hipStream_t stream) {
    (void)n_in; (void)out_size; (void)ws_size;
    const float* y_pred     = (const float*)d_in[0];
    const int*   labels     = (const int*)d_in[1];
    const int*   feat_lens  = (const int*)d_in[2];
    const int*   label_lens = (const int*)d_in[3];
    float* out = (float*)d_out;
    float* ws  = (float*)d_ws;
    const int B = in_sizes[2];  // 128
    ctc_kernel<<<B * 2, 128, 0, stream>>>(y_pred, labels, feat_lens, label_lens, ws);
    ctc_combine<<<B, 64, 0, stream>>>(ws, out);
}

// Round 2
// 250.376 us; speedup vs baseline: 1.0914x; 1.0844x over previous
//
#include <hip/hip_runtime.h>
#include <math.h>

#define EPSQ 1e-7f
#define TDIM 2000
#define CDIM 128
#define LDIM 200
#define SPL  7
#define SENTE (-(1 << 30))

// LDS int-index map (per block: ONE stream - alpha or beta)
// Ring: 64 rows x 128 floats = 8192 floats (32KB). Row slot:
//   alpha: slot = absolute_row & 63
//   beta:  slot = j & 63 where j = t0 - row (consumption index)
#define RING  0
#define LABSI 8192     // 200 ints
#define PRODF 8392     // pairs produced (producer k-counter)
#define CONSF 8393     // pairs fully consumed
#define SMEMN 8400

// workspace layout per batch: 1024 floats.
// [0..447] alpha vals (lane*7+j), int[448..511] alpha exps,
// [512..959] beta vals,           int[960..1023] beta exps.

__device__ __forceinline__ float dpp_shr_f(float x) { // lane i <- lane i-1, lane0 <- 0
    return __int_as_float(__builtin_amdgcn_update_dpp(0, __float_as_int(x), 0x138, 0xf, 0xf, true));
}
__device__ __forceinline__ int dpp_shr_i(int x) {
    return __builtin_amdgcn_update_dpp(0, x, 0x138, 0xf, 0xf, true);
}
__device__ __forceinline__ float dpp_shl_f(float x) { // lane i <- lane i+1, lane63 <- 0
    return __int_as_float(__builtin_amdgcn_update_dpp(0, __float_as_int(x), 0x130, 0xf, 0xf, true));
}
__device__ __forceinline__ int dpp_shl_i(int x) {
    return __builtin_amdgcn_update_dpp(0, x, 0x130, 0xf, 0xf, true);
}

// ---- alpha renorm (verified): per-lane BFP, neighbor = lane-1
__device__ __forceinline__ void renorm_alpha(float a[SPL], int& E, float& fprev, int lane) {
    float mx = fmaxf(fmaxf(fmaxf(a[0], a[1]), fmaxf(a[2], a[3])),
                     fmaxf(fmaxf(a[4], a[5]), a[6]));
    bool zero = (mx == 0.f);
    int e = ((__float_as_int(mx) >> 23) & 0xff) - 127;
    int S_self = zero ? SENTE : (E + e);
    int S1 = dpp_shr_i(S_self);
    if (lane == 0) S1 = SENTE;
    int S2 = dpp_shr_i(S1);
    if (lane == 0) S2 = SENTE;
    int E_new = max(S_self, S1);
    int E_prevnew = max(S1, S2);
    int dg = E - E_new;
    float g = (zero || dg < -126) ? 0.f : __int_as_float((dg + 127) << 23);
#pragma unroll
    for (int j = 0; j < SPL; ++j) a[j] *= g;
    E = E_new;
    int df = E_prevnew - E_new;
    bool fz = (E_prevnew <= SENTE / 2) || (df < -126);
    if (df > 126) df = 126;
    fprev = fz ? 0.f : __int_as_float((df + 127) << 23);
}

// ---- beta renorm: mirror, neighbor = lane+1
__device__ __forceinline__ void renorm_beta(float b[SPL], int& E, float& fnext, int lane) {
    float mx = fmaxf(fmaxf(fmaxf(b[0], b[1]), fmaxf(b[2], b[3])),
                     fmaxf(fmaxf(b[4], b[5]), b[6]));
    bool zero = (mx == 0.f);
    int e = ((__float_as_int(mx) >> 23) & 0xff) - 127;
    int S_self = zero ? SENTE : (E + e);
    int S1 = dpp_shl_i(S_self);
    if (lane == 63) S1 = SENTE;
    int S2 = dpp_shl_i(S1);
    if (lane == 63) S2 = SENTE;
    int E_new = max(S_self, S1);
    int E_nextnew = max(S1, S2);
    int dg = E - E_new;
    float g = (zero || dg < -126) ? 0.f : __int_as_float((dg + 127) << 23);
#pragma unroll
    for (int j = 0; j < SPL; ++j) b[j] *= g;
    E = E_new;
    int df = E_nextnew - E_new;
    bool fz = (E_nextnew <= SENTE / 2) || (df < -126);
    if (df > 126) df = 126;
    fnext = fz ? 0.f : __int_as_float((df + 127) << 23);
}

// ===== alpha MAIN step (branch-free, static LDS offsets; valid when t%64==1
// and no capture in [t, t+63]). Consumes reg slot (1+TOFF)&3 (row t+TOFF);
// prefetches row t+TOFF+3 -> ring slot (TOFF+4)&63 -> reg slot (TOFF)&3.
#define A_STEPF(TOFF) do {                                                    \
    float p6 = dpp_shr_f(a[6]) * fprev;                                       \
    float p5 = dpp_shr_f(a[5]) * fprev;                                       \
    float n0 = fmaf(skipf[0], p5,   a[0] + p6)   * q[(1+(TOFF))&3][0];        \
    float n1 = fmaf(skipf[1], p6,   a[1] + a[0]) * q[(1+(TOFF))&3][1];        \
    float n2 = fmaf(skipf[2], a[0], a[2] + a[1]) * q[(1+(TOFF))&3][2];        \
    float n3 = fmaf(skipf[3], a[1], a[3] + a[2]) * q[(1+(TOFF))&3][3];        \
    float n4 = fmaf(skipf[4], a[2], a[4] + a[3]) * q[(1+(TOFF))&3][4];        \
    float n5 = fmaf(skipf[5], a[3], a[5] + a[4]) * q[(1+(TOFF))&3][5];        \
    float n6 = fmaf(skipf[6], a[4], a[6] + a[5]) * q[(1+(TOFF))&3][6];        \
    a[0]=n0; a[1]=n1; a[2]=n2; a[3]=n3; a[4]=n4; a[5]=n5; a[6]=n6;            \
    _Pragma("unroll")                                                         \
    for (int j = 0; j < SPL; ++j)                                             \
        q[(TOFF)&3][j] = ring[((((TOFF)+4)&63)<<7) + cls[j]];                 \
} while (0);

// ===== alpha TAIL step (dynamic slot, with capture)
#define A_TAIL(TOFF) do {                                                     \
    float p6 = dpp_shr_f(a[6]) * fprev;                                       \
    float p5 = dpp_shr_f(a[5]) * fprev;                                       \
    float n0 = fmaf(skipf[0], p5,   a[0] + p6)   * q[(1+(TOFF))&3][0];        \
    float n1 = fmaf(skipf[1], p6,   a[1] + a[0]) * q[(1+(TOFF))&3][1];        \
    float n2 = fmaf(skipf[2], a[0], a[2] + a[1]) * q[(1+(TOFF))&3][2];        \
    float n3 = fmaf(skipf[3], a[1], a[3] + a[2]) * q[(1+(TOFF))&3][3];        \
    float n4 = fmaf(skipf[4], a[2], a[4] + a[3]) * q[(1+(TOFF))&3][4];        \
    float n5 = fmaf(skipf[5], a[3], a[5] + a[4]) * q[(1+(TOFF))&3][5];        \
    float n6 = fmaf(skipf[6], a[4], a[6] + a[5]) * q[(1+(TOFF))&3][6];        \
    a[0]=n0; a[1]=n1; a[2]=n2; a[3]=n3; a[4]=n4; a[5]=n5; a[6]=n6;            \
    if (t + (TOFF) == m) {                                                    \
        _Pragma("unroll")                                                     \
        for (int j = 0; j < SPL; ++j) ac[j] = a[j];                           \
        Eac = E;                                                              \
    }                                                                         \
    {   const int rr = ((t + (TOFF) + 3) & 63) << 7;                          \
        _Pragma("unroll")                                                     \
        for (int j = 0; j < SPL; ++j)                                         \
            q[(TOFF)&3][j] = ring[rr + cls[j]];                               \
    }                                                                         \
} while (0);

// ===== beta MAIN step (s%64==0). Consumes reg slot (SOFF)&3 (j = s+SOFF);
// prefetches j = s+SOFF+3 -> ring slot (SOFF+3)&63 -> reg slot (3+SOFF)&3.
#define B_STEPF(SOFF) do {                                                    \
    float c0 = bb[0]*q[(SOFF)&3][0], c1 = bb[1]*q[(SOFF)&3][1];               \
    float c2 = bb[2]*q[(SOFF)&3][2], c3 = bb[3]*q[(SOFF)&3][3];               \
    float c4 = bb[4]*q[(SOFF)&3][4], c5 = bb[5]*q[(SOFF)&3][5];               \
    float c6 = bb[6]*q[(SOFF)&3][6];                                          \
    float cn0 = dpp_shl_f(c0) * fnext;                                        \
    float cn1 = dpp_shl_f(c1) * fnext;                                        \
    bb[0] = fmaf(skb[0], c2, c0 + c1);                                        \
    bb[1] = fmaf(skb[1], c3, c1 + c2);                                        \
    bb[2] = fmaf(skb[2], c4, c2 + c3);                                        \
    bb[3] = fmaf(skb[3], c5, c3 + c4);                                        \
    bb[4] = fmaf(skb[4], c6, c4 + c5);                                        \
    bb[5] = fmaf(skb[5], cn0, c5 + c6);                                       \
    bb[6] = fmaf(skb[6], cn1, c6 + cn0);                                      \
    _Pragma("unroll")                                                         \
    for (int j = 0; j < SPL; ++j)                                             \
        q[(3+(SOFF))&3][j] = ring[((((SOFF)+3)&63)<<7) + cls[j]];             \
} while (0);

// ===== beta TAIL step (dynamic slot, with capture); slot by j = s+SOFF+3
#define B_TAIL(SOFF) do {                                                     \
    float c0 = bb[0]*q[(SOFF)&3][0], c1 = bb[1]*q[(SOFF)&3][1];               \
    float c2 = bb[2]*q[(SOFF)&3][2], c3 = bb[3]*q[(SOFF)&3][3];               \
    float c4 = bb[4]*q[(SOFF)&3][4], c5 = bb[5]*q[(SOFF)&3][5];               \
    float c6 = bb[6]*q[(SOFF)&3][6];                                          \
    float cn0 = dpp_shl_f(c0) * fnext;                                        \
    float cn1 = dpp_shl_f(c1) * fnext;                                        \
    bb[0] = fmaf(skb[0], c2, c0 + c1);                                        \
    bb[1] = fmaf(skb[1], c3, c1 + c2);                                        \
    bb[2] = fmaf(skb[2], c4, c2 + c3);                                        \
    bb[3] = fmaf(skb[3], c5, c3 + c4);                                        \
    bb[4] = fmaf(skb[4], c6, c4 + c5);                                        \
    bb[5] = fmaf(skb[5], cn0, c5 + c6);                                       \
    bb[6] = fmaf(skb[6], cn1, c6 + cn0);                                      \
    if (s + (SOFF) == scap) {                                                 \
        _Pragma("unroll")                                                     \
        for (int j = 0; j < SPL; ++j) bc[j] = bb[j];                          \
        Ebc = E;                                                              \
    }                                                                         \
    {   const int rr = ((s + (SOFF) + 3) & 63) << 7;                          \
        _Pragma("unroll")                                                     \
        for (int j = 0; j < SPL; ++j)                                         \
            q[(3+(SOFF))&3][j] = ring[rr + cls[j]];                           \
    }                                                                         \
} while (0);

#define ABLK(T) renorm_alpha(a, E, fprev, lane); \
    A_STEPF(T) A_STEPF((T)+1) A_STEPF((T)+2) A_STEPF((T)+3)
#define BBLK(T) renorm_beta(bb, E, fnext, lane); \
    B_STEPF(T) B_STEPF((T)+1) B_STEPF((T)+2) B_STEPF((T)+3)

// producer load/store of a group of 8 pairs (pair = 2 rows = 1KB).
#define LOADG(W, G) do {                                                      \
    _Pragma("unroll")                                                         \
    for (int i_ = 0; i_ < 8; ++i_) {                                          \
        int ii_ = (G) * 8 + i_; if (ii_ > iend) ii_ = iend;                   \
        int pr_ = role ? (pbase - ii_) : ii_;                                 \
        W[i_] = rp4[pr_ * 64 + lane];                                         \
    }                                                                         \
} while (0)

#define STOREG(W, G) do {                                                     \
    _Pragma("unroll")                                                         \
    for (int i_ = 0; i_ < 8; ++i_) {                                          \
        int ii_ = (G) * 8 + i_; if (ii_ > iend) ii_ = iend;                   \
        int pr_ = role ? (pbase - ii_) : ii_;                                 \
        float4 x_ = W[i_];                                                    \
        x_.x += EPSQ; x_.y += EPSQ; x_.z += EPSQ; x_.w += EPSQ;               \
        int fa_;                                                              \
        if (role) { int jj_ = (Tbm1 - 2 * pr_) - (lane >> 5);                 \
                    fa_ = ((jj_ & 63) << 7) + ((lane & 31) << 2); }           \
        else      { fa_ = ((pr_ & 31) << 8) + (lane << 2); }                  \
        *(float4*)&smf[RING + fa_] = x_;                                      \
    }                                                                         \
} while (0)

__global__ void __launch_bounds__(128, 1)
__attribute__((amdgpu_waves_per_eu(1, 1)))
ctc_kernel(const float* __restrict__ y_pred,
           const int* __restrict__ labels,
           const int* __restrict__ feat_lens,
           const int* __restrict__ label_lens,
           float* __restrict__ ws)
{
    __shared__ int smem[SMEMN];
    float* smf = (float*)smem;
    volatile int* vsm = (volatile int*)smem;

    const int bid = blockIdx.x;
    const int b = bid >> 1;
    const int role = bid & 1;          // 0 = alpha block, 1 = beta block
    const int tid = threadIdx.x;
    const int lane = tid & 63;
    const int wv = tid >> 6;

    int f = feat_lens[b];
    f = (f + 1) >> 1; f = (f + 1) >> 1;
    const int Tbm1 = f - 1;
    const int m = f >> 1;             // alpha: steps 1..m; beta: rows Tbm1..m+1

    if (tid < 2) smem[PRODF + tid] = 0;
    const int* labrow = labels + b * LDIM;
    for (int i = tid; i < LDIM; i += 128) smem[LABSI + i] = labrow[i];
    __syncthreads();

    const float4* rp4 = (const float4*)(y_pred + (size_t)b * TDIM * CDIM);

    if (wv == 1) {
        // ---------------- producer: 2-deep software pipeline ----------------
        int iend, pbase;
        if (role == 0) { iend = (m + 18) >> 1; pbase = 0; }
        else {
            const int pstart = Tbm1 >> 1;
            int pl = (m - 18) >> 1; if (pl < 0) pl = 0;
            iend = pstart - pl; pbase = pstart;
        }
        const int ng = (iend >> 3) + 1;
        float4 w0[8], w1[8];
        LOADG(w0, 0);
        if (ng > 1) LOADG(w1, 1);
        int g = 0;
        while (true) {
            while (vsm[CONSF] + 32 < 8 * (g + 1)) __builtin_amdgcn_s_sleep(2);
            asm volatile("" ::: "memory");
            STOREG(w0, g);
            asm volatile("s_waitcnt lgkmcnt(0)" ::: "memory");
            vsm[PRODF] = 8 * (g + 1);
            if (g + 2 < ng) LOADG(w0, g + 2);
            ++g; if (g >= ng) break;
            while (vsm[CONSF] + 32 < 8 * (g + 1)) __builtin_amdgcn_s_sleep(2);
            asm volatile("" ::: "memory");
            STOREG(w1, g);
            asm volatile("s_waitcnt lgkmcnt(0)" ::: "memory");
            vsm[PRODF] = 8 * (g + 1);
            if (g + 2 < ng) LOADG(w1, g + 2);
            ++g; if (g >= ng) break;
        }
        return;
    }

    // ---------------- consumer: per-lane state tables ----------------
    const int llen = label_lens[b];
    const int i1 = 2 * llen - 1, i2 = 2 * llen;
    int cls[SPL]; float skipf[SPL];
    const int s0 = lane * SPL;
#pragma unroll
    for (int j = 0; j < SPL; ++j) {
        int s = s0 + j;
        int c = CDIM - 1; float sk = 0.f;
        if (s < (2 * LDIM + 1) && (s & 1)) {
            int kk = s >> 1;
            c = smem[LABSI + kk];
            if (kk >= 1 && smem[LABSI + kk] != smem[LABSI + kk - 1]) sk = 1.f;
        }
        cls[j] = c; skipf[j] = sk;
    }
    const float* ring = &smf[RING];

    if (role == 0) {
        // ================= alpha (t = 0..m) =================
        float a[SPL], q[4][SPL], ac[SPL];
        int E = 0, Eac = 0;
        float fprev = 0.f;
#pragma unroll
        for (int j = 0; j < SPL; ++j) { a[j] = 0.f; ac[j] = 0.f; }

        while (vsm[PRODF] < 2) __builtin_amdgcn_s_sleep(1);
        asm volatile("" ::: "memory");
#pragma unroll
        for (int j = 0; j < SPL; ++j) {
            q[0][j] = ring[(0 << 7) + cls[j]];
            q[1][j] = ring[(1 << 7) + cls[j]];
            q[2][j] = ring[(2 << 7) + cls[j]];
            q[3][j] = ring[(3 << 7) + cls[j]];
        }
        if (lane == 0) { a[0] = q[0][0]; a[1] = q[0][1]; }

        int t = 1;
        // -------- main: 64 steps/iter, branch-free, static LDS offsets ------
        while (t + 64 <= m) {
            vsm[CONSF] = (t >= 2) ? (((t - 2) >> 1) + 1) : 0;
            {
                int need = ((t + 34) >> 1) + 1;
                while (vsm[PRODF] < need) __builtin_amdgcn_s_sleep(1);
                asm volatile("" ::: "memory");
            }
            ABLK(0) ABLK(4) ABLK(8) ABLK(12)
            ABLK(16) ABLK(20) ABLK(24) ABLK(28)
            {
                int tc = t + 32;
                vsm[CONSF] = ((tc - 2) >> 1) + 1;
                int need = ((tc + 34) >> 1) + 1;
                while (vsm[PRODF] < need) __builtin_amdgcn_s_sleep(1);
                asm volatile("" ::: "memory");
            }
            ABLK(32) ABLK(36) ABLK(40) ABLK(44)
            ABLK(48) ABLK(52) ABLK(56) ABLK(60)
            t += 64;
        }
        // -------- tail: 16 steps/iter with capture ------
        while (t <= m) {
            vsm[CONSF] = (t >= 2) ? (((t - 2) >> 1) + 1) : 0;
            int need = ((t + 18) >> 1) + 1;
            while (vsm[PRODF] < need) __builtin_amdgcn_s_sleep(1);
            asm volatile("" ::: "memory");
            renorm_alpha(a, E, fprev, lane);
            A_TAIL(0) A_TAIL(1) A_TAIL(2) A_TAIL(3)
            renorm_alpha(a, E, fprev, lane);
            A_TAIL(4) A_TAIL(5) A_TAIL(6) A_TAIL(7)
            renorm_alpha(a, E, fprev, lane);
            A_TAIL(8) A_TAIL(9) A_TAIL(10) A_TAIL(11)
            renorm_alpha(a, E, fprev, lane);
            A_TAIL(12) A_TAIL(13) A_TAIL(14) A_TAIL(15)
            t += 16;
        }
        vsm[CONSF] = 1 << 28;
        asm volatile("" ::: "memory");
        float* wsb = ws + (size_t)b * 1024;
#pragma unroll
        for (int j = 0; j < SPL; ++j) wsb[lane * SPL + j] = ac[j];
        ((int*)wsb)[448 + lane] = Eac;
    } else {
        // ================= beta (rows Tbm1 down to m+1) =================
        float bb[SPL], q[4][SPL], bc[SPL];
        int E = 0, Ebc = 0;
        float fnext = 0.f;
#pragma unroll
        for (int j = 0; j < SPL; ++j) {
            int s = s0 + j;
            bb[j] = (s == i1 || s == i2) ? 1.f : 0.f;
            bc[j] = 0.f;
        }
        float skb[SPL];
#pragma unroll
        for (int j = 0; j < 5; ++j) skb[j] = skipf[j + 2];
        skb[5] = (lane == 63) ? 0.f : __shfl_down(skipf[0], 1, 64);
        skb[6] = (lane == 63) ? 0.f : __shfl_down(skipf[1], 1, 64);

        const int t0 = Tbm1;
        const int nb = t0 - m;       // number of steps (>= 1)
        const int scap = nb - 1;
        const int pstart = t0 >> 1;

        while (vsm[PRODF] < 2) __builtin_amdgcn_s_sleep(1);
        asm volatile("" ::: "memory");
#pragma unroll
        for (int j = 0; j < SPL; ++j) {
            q[0][j] = ring[(0 << 7) + cls[j]];   // j-index 0 = row t0
            q[1][j] = ring[(1 << 7) + cls[j]];   // j-index 1
            q[2][j] = ring[(2 << 7) + cls[j]];   // j-index 2
            q[3][j] = 0.f;                       // filled by B step prefetch
        }

        int s = 0;
        // -------- main: 64 steps/iter, branch-free, static LDS offsets ------
        while (s + 64 <= scap) {
            {
                int tcur = t0 - s;
                vsm[CONSF] = pstart - ((tcur + 2) >> 1) + 1;
                int need = pstart - ((tcur - 34) >> 1) + 1;
                while (vsm[PRODF] < need) __builtin_amdgcn_s_sleep(1);
                asm volatile("" ::: "memory");
            }
            BBLK(0) BBLK(4) BBLK(8) BBLK(12)
            BBLK(16) BBLK(20) BBLK(24) BBLK(28)
            {
                int tcur = t0 - s - 32;
                vsm[CONSF] = pstart - ((tcur + 2) >> 1) + 1;
                int need = pstart - ((tcur - 34) >> 1) + 1;
                while (vsm[PRODF] < need) __builtin_amdgcn_s_sleep(1);
                asm volatile("" ::: "memory");
            }
            BBLK(32) BBLK(36) BBLK(40) BBLK(44)
            BBLK(48) BBLK(52) BBLK(56) BBLK(60)
            s += 64;
        }
        // -------- tail: 16 steps/iter with capture ------
        while (s < nb) {
            int tcur = t0 - s;
            vsm[CONSF] = pstart - ((tcur + 2) >> 1) + 1;
            int need = pstart - ((tcur - 18) >> 1) + 1;
            while (vsm[PRODF] < need) __builtin_amdgcn_s_sleep(1);
            asm volatile("" ::: "memory");
            renorm_beta(bb, E, fnext, lane);
            B_TAIL(0) B_TAIL(1) B_TAIL(2) B_TAIL(3)
            renorm_beta(bb, E, fnext, lane);
            B_TAIL(4) B_TAIL(5) B_TAIL(6) B_TAIL(7)
            renorm_beta(bb, E, fnext, lane);
            B_TAIL(8) B_TAIL(9) B_TAIL(10) B_TAIL(11)
            renorm_beta(bb, E, fnext, lane);
            B_TAIL(12) B_TAIL(13) B_TAIL(14) B_TAIL(15)
            s += 16;
        }
        vsm[CONSF] = 1 << 28;
        asm volatile("" ::: "memory");
        float* wsb = ws + (size_t)b * 1024 + 512;
#pragma unroll
        for (int j = 0; j < SPL; ++j) wsb[lane * SPL + j] = bc[j];
        ((int*)wsb)[448 + lane] = Ebc;
    }
}

__global__ void __launch_bounds__(64, 1)
ctc_combine(const float* __restrict__ ws, float* __restrict__ out)
{
    const int b = blockIdx.x;
    const int lane = threadIdx.x & 63;
    const float* wa = ws + (size_t)b * 1024;
    const float* wb = wa + 512;
    const int Ea = ((const int*)wa)[448 + lane];
    const int Eb = ((const int*)wb)[448 + lane];
    float dot = 0.f;
#pragma unroll
    for (int j = 0; j < SPL; ++j)
        dot = fmaf(wa[lane * SPL + j], wb[lane * SPL + j], dot);
    float l2 = (dot > 0.f) ? (log2f(dot) + (float)(Ea + Eb)) : -1e30f;
    float M = l2;
#pragma unroll
    for (int d = 1; d < 64; d <<= 1) M = fmaxf(M, __shfl_xor(M, d, 64));
    float S = exp2f(l2 - M);
#pragma unroll
    for (int d = 1; d < 64; d <<= 1) S += __shfl_xor(S, d, 64);
    if (lane == 0) out[b] = -(M + log2f(S)) * 0.69314718055994530942f;
}

extern "C" void kernel_launch(void* const* d_in, const int* in_sizes, int n_in,
                              void* d_out, int out_size, void* d_ws, size_t ws_size,
                              hipStream_t stream) {
    (void)n_in; (void)out_size; (void)ws_size;
    const float* y_pred     = (const float*)d_in[0];
    const int*   labels     = (const int*)d_in[1];
    const int*   feat_lens  = (const int*)d_in[2];
    const int*   label_lens = (const int*)d_in[3];
    float* out = (float*)d_out;
    float* ws  = (float*)d_ws;
    const int B = in_sizes[2];  // 128
    ctc_kernel<<<B * 2, 128, 0, stream>>>(y_pred, labels, feat_lens, label_lens, ws);
    ctc_combine<<<B, 64, 0, stream>>>(ws, out);
}